// Round 8
// baseline (129.669 us; speedup 1.0000x reference)
//
#include <hip/hip_runtime.h>
#include <stdint.h>

#define NQ 10
#define DIMQ 1024
#define BATCH 4096

// Layer's 10 CNOTs composed as a GF(2)-linear index map (scatter form).
__host__ __device__ constexpr int cperm_c(int x, int r) {
  for (int q = 0; q < NQ; ++q) {
    const int c = 9 - q;
    int t = c - r; if (t < 0) t += NQ;
    x ^= ((x >> c) & 1) << t;
  }
  return x;
}

// ---- VALU-pipe lane shuffles (R6/R7 lesson: __shfl_xor = ds_bpermute on the
// shared DS pipe; DPP/permlane are VALU-pipe and were the 76->62 win). ----
template<int CTRL>
__device__ __forceinline__ float dpp1(float x) {
  return __int_as_float(
      __builtin_amdgcn_update_dpp(0, __float_as_int(x), CTRL, 0xF, 0xF, true));
}
// quad_perm xor1=0xB1, xor2=0x4E, xor3=0x1B; row_mirror(^15)=0x140,
// row_half_mirror(^7)=0x141. ^4 = ^7 o ^3, ^8 = ^15 o ^7.
template<int P>   // P = lane bit, 0..4
__device__ __forceinline__ float shufl(float x) {
  if constexpr (P == 0)      return dpp1<0xB1>(x);
  else if constexpr (P == 1) return dpp1<0x4E>(x);
  else if constexpr (P == 2) return dpp1<0x141>(dpp1<0x1B>(x));
  else if constexpr (P == 3) return dpp1<0x140>(dpp1<0x141>(x));
  else return __int_as_float(
      __builtin_amdgcn_ds_swizzle(__float_as_int(x), 0x401F));  // ^16
}

// Register-bit rotation (idx bits 9:6). Explicit scalar FMA form: negations
// fold into VOP3 src modifiers (R7 post-mortem: cswap temps cost ~3K extra
// ops/wave).
template<int MT>
__device__ __forceinline__ void rotR(float (&sR)[16], float (&sI)[16],
                                     float4 A, float4 B) {
  #pragma unroll
  for (int e0 = 0; e0 < 16; ++e0) {
    if (e0 & MT) continue;
    const int e1 = e0 | MT;
    float x0 = sR[e0], y0 = sI[e0], x1 = sR[e1], y1 = sI[e1];
    sR[e0] = A.x*x0 - A.y*y0 + A.z*x1 - A.w*y1;
    sI[e0] = A.x*y0 + A.y*x0 + A.z*y1 + A.w*x1;
    sR[e1] = B.x*x0 - B.y*y0 + B.z*x1 - B.w*y1;
    sI[e1] = B.x*y0 + B.y*x0 + B.z*y1 + B.w*x1;
  }
}

// Lane-bit rotation, bits 0..4 (DPP / swizzle partner).
template<int P>
__device__ __forceinline__ void rotL(float (&sR)[16], float (&sI)[16],
                                     float4 A, float4 B, int lane) {
  const int L = (lane >> P) & 1;
  const float aR = L ? B.z : A.x, aI = L ? B.w : A.y;
  const float bR = L ? B.x : A.z, bI = L ? B.y : A.w;
  #pragma unroll
  for (int e = 0; e < 16; ++e) {
    float oR = shufl<P>(sR[e]), oI = shufl<P>(sI[e]);
    float x = sR[e], y = sI[e];
    sR[e] = aR*x - aI*y + bR*oR - bI*oI;
    sI[e] = aR*y + aI*x + bR*oI + bI*oR;
  }
}

// Lane-bit 5 (xor32): v_permlane32_swap (VALU; R7-verified pattern).
__device__ __forceinline__ void rot5(float (&sR)[16], float (&sI)[16],
                                     float4 A, float4 B, int lane) {
  const int L = lane >> 5;
  const float aR = L ? B.z : A.x, aI = L ? B.w : A.y;
  const float bR = L ? B.x : A.z, bI = L ? B.y : A.w;
  #pragma unroll
  for (int e = 0; e < 16; ++e) {
    unsigned xr = __float_as_uint(sR[e]), xi = __float_as_uint(sI[e]);
    auto rr = __builtin_amdgcn_permlane32_swap(xr, xr, false, false);
    auto ri = __builtin_amdgcn_permlane32_swap(xi, xi, false, false);
    float oR = __uint_as_float(L ? rr[0] : rr[1]);
    float oI = __uint_as_float(L ? ri[0] : ri[1]);
    float x = sR[e], y = sI[e];
    sR[e] = aR*x - aI*y + bR*oR - bI*oI;
    sI[e] = aR*y + aI*x + bR*oI + bI*oR;
  }
}

// CNOT permutation via private per-wave LDS slice (same-wave DS in-order,
// no barrier).
template<int R>
__device__ __forceinline__ void perm_state(float (&sR)[16], float (&sI)[16],
                                           float2* __restrict__ L, int lane) {
  constexpr int K0=cperm_c(1,R),  K1=cperm_c(2,R),  K2=cperm_c(4,R),
                K3=cperm_c(8,R),  K4=cperm_c(16,R), K5=cperm_c(32,R),
                C6=cperm_c(64,R), C7=cperm_c(128,R),
                C8=cperm_c(256,R),C9=cperm_c(512,R);
  const int yl = ((lane & 1)  ? K0 : 0) ^ ((lane & 2)  ? K1 : 0) ^
                 ((lane & 4)  ? K2 : 0) ^ ((lane & 8)  ? K3 : 0) ^
                 ((lane & 16) ? K4 : 0) ^ ((lane & 32) ? K5 : 0);
  #pragma unroll
  for (int e = 0; e < 16; ++e) {
    const int ye = ((e & 1) ? C6 : 0) ^ ((e & 2) ? C7 : 0) ^
                   ((e & 4) ? C8 : 0) ^ ((e & 8) ? C9 : 0);
    L[yl ^ ye] = make_float2(sR[e], sI[e]);
  }
  #pragma unroll
  for (int e = 0; e < 16; ++e) {
    float2 t = L[(e << 6) | lane];
    sR[e] = t.x; sI[e] = t.y;
  }
}

// Wave sum -> uniform scalar: DPP tree ^1..^8, swizzle ^16, then
// permlane32_swap sum-of-halves (uniform result, no readlane).
__device__ __forceinline__ float red64(float v) {
  v += dpp1<0xB1>(v);
  v += dpp1<0x4E>(v);
  v += dpp1<0x141>(dpp1<0x1B>(v));   // ^4
  v += dpp1<0x140>(dpp1<0x141>(v));  // ^8
  v += __int_as_float(__builtin_amdgcn_ds_swizzle(__float_as_int(v), 0x401F));
  auto p = __builtin_amdgcn_permlane32_swap(__float_as_uint(v),
                                            __float_as_uint(v), false, false);
  return __uint_as_float(p[0]) + __uint_as_float(p[1]);
}

template<int LYR>
__device__ __forceinline__ void do_layer(float (&sR)[16], float (&sI)[16],
                                         const float4* __restrict__ gq,
                                         float2* __restrict__ L, int lane) {
  const float4* G = gq + LYR * 20;
  rotR<8>(sR, sI, G[0],  G[1]);          // q0 -> bit9
  rotR<4>(sR, sI, G[2],  G[3]);          // q1 -> bit8
  rotR<2>(sR, sI, G[4],  G[5]);          // q2 -> bit7
  rotR<1>(sR, sI, G[6],  G[7]);          // q3 -> bit6
  rot5   (sR, sI, G[8],  G[9],  lane);   // q4 -> bit5 (permlane32_swap)
  rotL<4>(sR, sI, G[10], G[11], lane);   // q5 -> bit4 (ds_swizzle xor16)
  rotL<3>(sR, sI, G[12], G[13], lane);   // q6 -> bit3 (DPP)
  rotL<2>(sR, sI, G[14], G[15], lane);   // q7 -> bit2 (DPP)
  rotL<1>(sR, sI, G[16], G[17], lane);   // q8 -> bit1 (DPP)
  rotL<0>(sR, sI, G[18], G[19], lane);   // q9 -> bit0 (DPP)
  if constexpr (LYR < 3) perm_state<LYR + 1>(sR, sI, L, lane);
  // layer 3's permutation (r=4) is folded into the epilogue sign masks
}

// ------------------------------------------------- single fused dispatch ---
// R7 post-mortem: wall - kernel ~= 51-58 us in every 2-kernel round; the
// prep_g launch + stream dependency is the suspect. One kernel: block
// computes the 40 gates into LDS (one barrier), then barrier-free per-wave
// simulation. One row per wave, 16 complex amps/lane, idx=(e<<6)|lane.
__global__ __launch_bounds__(256, 2) void vqc_all(const float* __restrict__ X,
                                                  const float* __restrict__ wts,
                                                  const float* __restrict__ W,
                                                  const float* __restrict__ bias,
                                                  float* __restrict__ out) {
  __shared__ float4 gq[80];          // 40 gates x {A=(aR,aI,bR,bI), B=(cR,cI,dR,dI)}
  __shared__ float2 lds[4][DIMQ];    // 32 KB perm slices (per-wave private)
  const int tid = threadIdx.x;
  if (tid < 40) {
    float phi = wts[tid * 3 + 0], th = wts[tid * 3 + 1], om = wts[tid * 3 + 2];
    float ct = cosf(0.5f * th), s = sinf(0.5f * th);
    float ap = 0.5f * (phi + om), am = 0.5f * (phi - om);
    float cp = cosf(ap), spp = sinf(ap), cm = cosf(am), sm = sinf(am);
    gq[2 * tid + 0] = make_float4(ct * cp, -ct * spp, -s * cm, -s * sm);
    gq[2 * tid + 1] = make_float4(s * cm, -s * sm, ct * cp, ct * spp);
  }
  __syncthreads();                   // the only barrier in the kernel

  const int lane = tid & 63;
  const int w = tid >> 6;
  const int row = blockIdx.x * 4 + w;
  float2* L = lds[w];

  float sR[16], sI[16];

  // ---- load (coalesced; norm deferred) ----
  const float* xr = X + (size_t)row * DIMQ;
  float ss = 0.f;
  #pragma unroll
  for (int e = 0; e < 16; ++e) {
    sR[e] = xr[(e << 6) | lane];
    sI[e] = 0.f;
    ss += sR[e] * sR[e];
  }
  const float rn2 = 1.0f / red64(ss);   // uniform probability scale

  do_layer<0>(sR, sI, gq, L, lane);
  do_layer<1>(sR, sI, gq, L, lane);
  do_layer<2>(sR, sI, gq, L, lane);
  do_layer<3>(sR, sI, gq, L, lane);

  // ---- probs -> z (layer-3 perm r=4 folded into signs) ----
  constexpr int R4 = 4;
  constexpr int K0=cperm_c(1,R4),  K1=cperm_c(2,R4),  K2=cperm_c(4,R4),
                K3=cperm_c(8,R4),  K4=cperm_c(16,R4), K5=cperm_c(32,R4),
                C6=cperm_c(64,R4), C7=cperm_c(128,R4),
                C8=cperm_c(256,R4),C9=cperm_c(512,R4);
  const int yl = ((lane & 1)  ? K0 : 0) ^ ((lane & 2)  ? K1 : 0) ^
                 ((lane & 4)  ? K2 : 0) ^ ((lane & 8)  ? K3 : 0) ^
                 ((lane & 16) ? K4 : 0) ^ ((lane & 32) ? K5 : 0);
  float z[10];
  #pragma unroll
  for (int q = 0; q < 10; ++q) z[q] = 0.f;
  #pragma unroll
  for (int e = 0; e < 16; ++e) {
    const int y = yl ^ (((e & 1) ? C6 : 0) ^ ((e & 2) ? C7 : 0) ^
                        ((e & 4) ? C8 : 0) ^ ((e & 8) ? C9 : 0));
    const float pr = sR[e] * sR[e] + sI[e] * sI[e];
    #pragma unroll
    for (int q = 0; q < 10; ++q)
      z[q] += ((y >> (9 - q)) & 1) ? -pr : pr;
  }
  #pragma unroll
  for (int q = 0; q < 10; ++q) z[q] = red64(z[q]) * rn2;   // uniform

  // ---- linear head ----
  if (lane < 16) {
    float acc = bias[lane];
    #pragma unroll
    for (int q = 0; q < 10; ++q) acc += z[q] * W[lane * 10 + q];
    out[(size_t)row * 16 + lane] = acc;
  }
}

extern "C" void kernel_launch(void* const* d_in, const int* in_sizes, int n_in,
                              void* d_out, int out_size, void* d_ws, size_t ws_size,
                              hipStream_t stream) {
  const float* X    = (const float*)d_in[0];
  const float* wts  = (const float*)d_in[1];
  const float* W    = (const float*)d_in[2];
  const float* bias = (const float*)d_in[3];
  float* out = (float*)d_out;
  hipLaunchKernelGGL(vqc_all, dim3(BATCH / 4), dim3(256), 0, stream,
                     X, wts, W, bias, out);
}

// Round 9
// 103.203 us; speedup vs baseline: 1.2565x; 1.2565x over previous
//
#include <hip/hip_runtime.h>
#include <stdint.h>

#define NQ 10
#define DIMQ 1024
#define BATCH 4096

typedef float f32x2 __attribute__((ext_vector_type(2)));

// ------------------------------------------------------- gate coefficients ---
// Per gate: 8 pre-packed f32x2 pairs so every butterfly term is
// coef*v + coef2*swap(v) (pure v_pk_fma_f32, negations baked into the data):
// C[0]=(aR,aR) C[1]=(-aI,aI) C[2]=(bR,bR) C[3]=(-bI,bI)
// C[4]=(cR,cR) C[5]=(-cI,cI) C[6]=(dR,dR) C[7]=(-dI,dI)
__global__ __launch_bounds__(64) void prep_g(const float* __restrict__ wts,
                                             float* __restrict__ Gg) {
  int g = threadIdx.x;
  if (g < 40) {
    float phi = wts[g * 3 + 0], th = wts[g * 3 + 1], om = wts[g * 3 + 2];
    float ct = cosf(0.5f * th), s = sinf(0.5f * th);
    float ap = 0.5f * (phi + om), am = 0.5f * (phi - om);
    float cp = cosf(ap), spp = sinf(ap), cm = cosf(am), sm = sinf(am);
    float aR = ct * cp,  aI = -ct * spp;
    float bR = -s * cm,  bI = -s * sm;
    float cR = s * cm,   cI = -s * sm;
    float dR = ct * cp,  dI = ct * spp;
    float* o = Gg + g * 16;
    o[0]  = aR;  o[1]  = aR;  o[2]  = -aI; o[3]  = aI;
    o[4]  = bR;  o[5]  = bR;  o[6]  = -bI; o[7]  = bI;
    o[8]  = cR;  o[9]  = cR;  o[10] = -cI; o[11] = cI;
    o[12] = dR;  o[13] = dR;  o[14] = -dI; o[15] = dI;
  }
}

// Layer's 10 CNOTs composed as a GF(2)-linear index map (scatter form).
__host__ __device__ constexpr int cperm_c(int x, int r) {
  for (int q = 0; q < NQ; ++q) {
    const int c = 9 - q;
    int t = c - r; if (t < 0) t += NQ;
    x ^= ((x >> c) & 1) << t;
  }
  return x;
}
// Epilogue sign masks (layer-3 perm r=4 folded into signs):
// sign(q, idx) = (-1)^{parity(lane & amask(q))} * (-1)^{parity(e & mmask(q))}
constexpr int amask(int q) {
  int a = 0;
  for (int b = 0; b < 6; ++b) a |= ((cperm_c(1 << b, 4) >> (9 - q)) & 1) << b;
  return a;
}
constexpr int mmask(int q) {
  int m = 0;
  for (int b = 0; b < 4; ++b) m |= ((cperm_c(1 << (6 + b), 4) >> (9 - q)) & 1) << b;
  return m;
}

__device__ __forceinline__ f32x2 swapv(f32x2 v) {
  return __builtin_shufflevector(v, v, 1, 0);
}

// ---- VALU-pipe lane shuffles (R7-proven: DPP/permlane, not ds_bpermute) ----
template<int CTRL>
__device__ __forceinline__ float dpp1(float x) {
  return __int_as_float(
      __builtin_amdgcn_update_dpp(0, __float_as_int(x), CTRL, 0xF, 0xF, true));
}
// quad_perm xor1=0xB1, xor2=0x4E, xor3=0x1B; row_mirror(^15)=0x140,
// row_half_mirror(^7)=0x141. ^4 = ^7 o ^3, ^8 = ^15 o ^7.
template<int P>   // P = lane bit, 0..4
__device__ __forceinline__ float shufl(float x) {
  if constexpr (P == 0)      return dpp1<0xB1>(x);
  else if constexpr (P == 1) return dpp1<0x4E>(x);
  else if constexpr (P == 2) return dpp1<0x141>(dpp1<0x1B>(x));
  else if constexpr (P == 3) return dpp1<0x140>(dpp1<0x141>(x));
  else return __int_as_float(
      __builtin_amdgcn_ds_swizzle(__float_as_int(x), 0x401F));  // ^16
}

// Register-bit rotation (idx bits 9:6). Packed complex butterfly.
template<int MT>
__device__ __forceinline__ void rotR(f32x2 (&s)[16], const f32x2* __restrict__ C) {
  const f32x2 C0 = C[0], C1 = C[1], C2 = C[2], C3 = C[3];
  const f32x2 C4 = C[4], C5 = C[5], C6 = C[6], C7 = C[7];
  #pragma unroll
  for (int e0 = 0; e0 < 16; ++e0) {
    if (e0 & MT) continue;
    const int e1 = e0 | MT;
    f32x2 x0 = s[e0], x1 = s[e1], w0 = swapv(x0), w1 = swapv(x1);
    s[e0] = C0 * x0 + C1 * w0 + C2 * x1 + C3 * w1;
    s[e1] = C4 * x0 + C5 * w0 + C6 * x1 + C7 * w1;
  }
}

// Lane-bit rotation, bits 0..4 (DPP / swizzle partner).
template<int P>
__device__ __forceinline__ void rotL(f32x2 (&s)[16], const f32x2* __restrict__ C,
                                     int lane) {
  const int L = (lane >> P) & 1;
  const f32x2 A0 = L ? C[6] : C[0], A1 = L ? C[7] : C[1];
  const f32x2 B0 = L ? C[4] : C[2], B1 = L ? C[5] : C[3];
  #pragma unroll
  for (int e = 0; e < 16; ++e) {
    f32x2 o;
    o.x = shufl<P>(s[e].x);
    o.y = shufl<P>(s[e].y);
    s[e] = A0 * s[e] + A1 * swapv(s[e]) + B0 * o + B1 * swapv(o);
  }
}

// Lane-bit 5 (xor32): v_permlane32_swap (VALU; R7-verified select pattern).
__device__ __forceinline__ void rot5(f32x2 (&s)[16], const f32x2* __restrict__ C,
                                     int lane) {
  const int L = lane >> 5;
  const f32x2 A0 = L ? C[6] : C[0], A1 = L ? C[7] : C[1];
  const f32x2 B0 = L ? C[4] : C[2], B1 = L ? C[5] : C[3];
  #pragma unroll
  for (int e = 0; e < 16; ++e) {
    unsigned xr = __float_as_uint(s[e].x), xi = __float_as_uint(s[e].y);
    auto rr = __builtin_amdgcn_permlane32_swap(xr, xr, false, false);
    auto ri = __builtin_amdgcn_permlane32_swap(xi, xi, false, false);
    f32x2 o;
    o.x = __uint_as_float(L ? rr[0] : rr[1]);
    o.y = __uint_as_float(L ? ri[0] : ri[1]);
    s[e] = A0 * s[e] + A1 * swapv(s[e]) + B0 * o + B1 * swapv(o);
  }
}

// CNOT permutation via private per-wave LDS slice (same-wave DS in-order,
// no barrier).
template<int R>
__device__ __forceinline__ void perm_state(f32x2 (&s)[16], f32x2* __restrict__ L,
                                           int lane) {
  constexpr int K0=cperm_c(1,R),  K1=cperm_c(2,R),  K2=cperm_c(4,R),
                K3=cperm_c(8,R),  K4=cperm_c(16,R), K5=cperm_c(32,R),
                C6=cperm_c(64,R), C7=cperm_c(128,R),
                C8=cperm_c(256,R),C9=cperm_c(512,R);
  const int yl = ((lane & 1)  ? K0 : 0) ^ ((lane & 2)  ? K1 : 0) ^
                 ((lane & 4)  ? K2 : 0) ^ ((lane & 8)  ? K3 : 0) ^
                 ((lane & 16) ? K4 : 0) ^ ((lane & 32) ? K5 : 0);
  #pragma unroll
  for (int e = 0; e < 16; ++e) {
    const int ye = ((e & 1) ? C6 : 0) ^ ((e & 2) ? C7 : 0) ^
                   ((e & 4) ? C8 : 0) ^ ((e & 8) ? C9 : 0);
    L[yl ^ ye] = s[e];
  }
  #pragma unroll
  for (int e = 0; e < 16; ++e) s[e] = L[(e << 6) | lane];
}

// Wave sum -> uniform scalar: DPP tree ^1..^8, swizzle ^16, permlane32 halves.
__device__ __forceinline__ float red64(float v) {
  v += dpp1<0xB1>(v);
  v += dpp1<0x4E>(v);
  v += dpp1<0x141>(dpp1<0x1B>(v));   // ^4
  v += dpp1<0x140>(dpp1<0x141>(v));  // ^8
  v += __int_as_float(__builtin_amdgcn_ds_swizzle(__float_as_int(v), 0x401F));
  auto p = __builtin_amdgcn_permlane32_swap(__float_as_uint(v),
                                            __float_as_uint(v), false, false);
  return __uint_as_float(p[0]) + __uint_as_float(p[1]);
}

template<int LYR>
__device__ __forceinline__ void do_layer(f32x2 (&s)[16],
                                         const f32x2* __restrict__ Cq,
                                         f32x2* __restrict__ L, int lane) {
  const f32x2* G = Cq + LYR * 80;      // 10 gates x 8 f32x2
  rotR<8>(s, G + 0);           // q0 -> bit9
  rotR<4>(s, G + 8);           // q1 -> bit8
  rotR<2>(s, G + 16);          // q2 -> bit7
  rotR<1>(s, G + 24);          // q3 -> bit6
  rot5   (s, G + 32, lane);    // q4 -> bit5 (permlane32_swap)
  rotL<4>(s, G + 40, lane);    // q5 -> bit4 (ds_swizzle xor16)
  rotL<3>(s, G + 48, lane);    // q6 -> bit3 (DPP)
  rotL<2>(s, G + 56, lane);    // q7 -> bit2 (DPP)
  rotL<1>(s, G + 64, lane);    // q8 -> bit1 (DPP)
  rotL<0>(s, G + 72, lane);    // q9 -> bit0 (DPP)
  if constexpr (LYR < 3) perm_state<LYR + 1>(s, L, lane);
  // layer 3's permutation (r=4) is folded into the epilogue sign masks
}

// In-register Walsh-Hadamard stage over the 4 e-bits.
template<int M>
__device__ __forceinline__ void wht(float (&h)[16]) {
  #pragma unroll
  for (int e0 = 0; e0 < 16; ++e0) {
    if (e0 & M) continue;
    float u = h[e0], v = h[e0 | M];
    h[e0] = u + v;
    h[e0 | M] = u - v;
  }
}

// z_q = red64( (+-) WHT(p)[mmask(q)] ) * rn2, lane sign = parity(lane&amask).
template<int Q>
__device__ __forceinline__ float zfin(const float (&h)[16], int lane, float rn2) {
  constexpr int aq = amask(Q);
  constexpr int mq = mmask(Q);
  float t = h[mq];
  if constexpr (aq != 0) {
    int par = __builtin_popcount(lane & aq) & 1;
    t = par ? -t : t;
  }
  return red64(t) * rn2;
}

// ------------------------------------------------------- fused simulation ---
// One row per wave, 16 complex amps/lane, idx=(e<<6)|lane. All shuffles on
// the VALU pipe except xor16 + the 3 CNOT perms. Zero __syncthreads.
// R8 post-mortem: f32x2 packed math (v_pk_fma_f32) is the fast form; gate
// coefs from GLOBAL uniform (s_load -> SGPR operands), NOT LDS.
__global__ __launch_bounds__(256, 2) void vqc_sim(const float* __restrict__ X,
                                                  const float* __restrict__ Gg,
                                                  const float* __restrict__ W,
                                                  const float* __restrict__ bias,
                                                  float* __restrict__ out) {
  __shared__ f32x2 lds[4][DIMQ];     // 32 KB perm slices (per-wave private)
  const int lane = threadIdx.x & 63;
  const int w = threadIdx.x >> 6;
  const int row = blockIdx.x * 4 + w;
  f32x2* L = lds[w];
  const f32x2* Cq = (const f32x2*)Gg;

  f32x2 s[16];

  // ---- load (coalesced; norm deferred) ----
  const float* xr = X + (size_t)row * DIMQ;
  float ss = 0.f;
  #pragma unroll
  for (int e = 0; e < 16; ++e) {
    s[e].x = xr[(e << 6) | lane];
    s[e].y = 0.f;
    ss += s[e].x * s[e].x;
  }
  const float rn2 = 1.0f / red64(ss);   // uniform probability scale

  do_layer<0>(s, Cq, L, lane);
  do_layer<1>(s, Cq, L, lane);
  do_layer<2>(s, Cq, L, lane);
  do_layer<3>(s, Cq, L, lane);

  // ---- probs -> z via WHT factorization (R8 epilogue cut) ----
  float h[16];
  #pragma unroll
  for (int e = 0; e < 16; ++e) h[e] = s[e].x * s[e].x + s[e].y * s[e].y;
  wht<1>(h); wht<2>(h); wht<4>(h); wht<8>(h);

  float z[10];
  z[0] = zfin<0>(h, lane, rn2);
  z[1] = zfin<1>(h, lane, rn2);
  z[2] = zfin<2>(h, lane, rn2);
  z[3] = zfin<3>(h, lane, rn2);
  z[4] = zfin<4>(h, lane, rn2);
  z[5] = zfin<5>(h, lane, rn2);
  z[6] = zfin<6>(h, lane, rn2);
  z[7] = zfin<7>(h, lane, rn2);
  z[8] = zfin<8>(h, lane, rn2);
  z[9] = zfin<9>(h, lane, rn2);

  // ---- linear head ----
  if (lane < 16) {
    float acc = bias[lane];
    #pragma unroll
    for (int q = 0; q < 10; ++q) acc += z[q] * W[lane * 10 + q];
    out[(size_t)row * 16 + lane] = acc;
  }
}

extern "C" void kernel_launch(void* const* d_in, const int* in_sizes, int n_in,
                              void* d_out, int out_size, void* d_ws, size_t ws_size,
                              hipStream_t stream) {
  const float* X    = (const float*)d_in[0];
  const float* wts  = (const float*)d_in[1];
  const float* W    = (const float*)d_in[2];
  const float* bias = (const float*)d_in[3];
  float* out = (float*)d_out;
  float* Gg = (float*)d_ws;   // 40 gates x 16 floats = 2.5 KB

  hipLaunchKernelGGL(prep_g,  dim3(1),         dim3(64),  0, stream, wts, Gg);
  hipLaunchKernelGGL(vqc_sim, dim3(BATCH / 4), dim3(256), 0, stream, X, Gg, W, bias, out);
}